// Round 4
// baseline (172.392 us; speedup 1.0000x reference)
//
#include <hip/hip_runtime.h>
#include <math.h>

// Problem constants (match reference setup_inputs)
#define B_N   8192      // samples
#define Z_D   128       // feature dim
#define P_N   93        // proxies
#define NCLS  62        // classes
#define A_N   2730      // anchors: arange(0, 8189, 3)
#define BCAP  256       // class-bucket capacity (max expected ~180)
#define GT_S  96        // GT row stride (float4-aligned)
#define NBLK  256       // grid size — one block per CU, all co-resident
#define MAGIC 0x5eedf00d
#define TWO_EPS   2e-6f
#define ZEPS2     (128.0f * 1e-6f * 1e-6f)

__device__ __forceinline__ float wave_sum(float v) {
#pragma unroll
  for (int off = 1; off < 64; off <<= 1) v += __shfl_xor(v, off, 64);
  return v;
}
__device__ __forceinline__ float wave_min(float v) {
#pragma unroll
  for (int off = 1; off < 64; off <<= 1) v = fminf(v, __shfl_xor(v, off, 64));
  return v;
}

// Grid-wide barrier: device-scope release add + acquire spin. Safe because
// grid == 256 blocks == CU count (all blocks resident). Guard bound avoids
// a hang if an assumption ever breaks (gives wrong answer instead).
__device__ __forceinline__ void gbar(int* ctr) {
  __syncthreads();
  if (threadIdx.x == 0) {
    __threadfence();  // make this block's stores visible device-wide
    __hip_atomic_fetch_add(ctr, 1, __ATOMIC_RELEASE, __HIP_MEMORY_SCOPE_AGENT);
    long long guard = 0;
    while (__hip_atomic_load(ctr, __ATOMIC_ACQUIRE, __HIP_MEMORY_SCOPE_AGENT) < NBLK) {
      __builtin_amdgcn_s_sleep(8);
      if (++guard > (1LL << 27)) break;
    }
  }
  __syncthreads();
}

__global__ __launch_bounds__(256) void kFused(
    const float* __restrict__ z, const int* __restrict__ y_idx,
    const float* __restrict__ prox, const int* __restrict__ y_map,
    float* __restrict__ out,
    int* flag, int* bar0, int* bar1, float* accf,
    float* __restrict__ pp, float* __restrict__ sp,
    float* __restrict__ zz, float* __restrict__ sz, float* __restrict__ w,
    int* __restrict__ yrel, int* __restrict__ cnt, int* __restrict__ bkt,
    float* __restrict__ GT) {
  __shared__ float pt[12 * Z_D];   // P1: proxy tile; P2: reused for pp/sp cache
  __shared__ float part[4];
  __shared__ int lcnt;
  const int b = blockIdx.x, tid = threadIdx.x;
  const int lane = tid & 63, wv = tid >> 6;

  // --- init: zero barrier counters + accumulator, release MAGIC flag ------
  // ws is poisoned 0xAA each launch; 0xAAAAAAAA != MAGIC so the flag protocol
  // is race-free against garbage.
  if (b == 0 && tid == 0) {
    bar0[0] = 0; bar1[0] = 0; accf[0] = 0.0f;
    __hip_atomic_store(flag, MAGIC, __ATOMIC_RELEASE, __HIP_MEMORY_SCOPE_AGENT);
  }

  // --- P0: class buckets (blocks 0..61). y_map entries are unique, so block
  // c claims exactly the samples with y_idx == y_map[c]; every j is claimed
  // by exactly one block => yrel fully written, no cross-block atomics. ----
  if (b < NCLS) {
    if (tid == 0) lcnt = 0;
    __syncthreads();
    const int ym = y_map[b];
    for (int jj = tid; jj < B_N; jj += 256) {
      if (y_idx[jj] == ym) {
        yrel[jj] = b;
        const int pos = atomicAdd(&lcnt, 1);   // LDS atomic
        if (pos < BCAP) bkt[b * BCAP + pos] = jj;
      }
    }
    __syncthreads();
    if (tid == 0) cnt[b] = min(lcnt, BCAP);
  }

  // --- P1: every block normalizes its own 12-proxy tile into LDS, then
  // computes GT[j][k] = p_hat_k . z_j for its (jchunk, ktile). ------------
  const int khalf = b >> 5;       // 0..7  -> proxies khalf*12 .. +11
  const int jch   = b & 31;       // 0..31 -> rows jch*256 .. +255
  const int k0    = khalf * 12;
#pragma unroll
  for (int r = 0; r < 3; ++r) {
    const int rl = wv * 3 + r;            // 0..11 within tile
    const int k = k0 + rl;
    float a = 0.0f, c2 = 0.0f;
    if (k < P_N) { a = prox[k * Z_D + lane]; c2 = prox[k * Z_D + 64 + lane]; }
    const float s = wave_sum(a + c2);
    const float q = wave_sum(a * a + c2 * c2);
    float inv = 1.0f / fmaxf(sqrtf(q), 1e-12f);
    if (k >= P_N) inv = 0.0f;             // zero pad rows 93..95
    pt[rl * Z_D + lane] = a * inv;
    pt[rl * Z_D + 64 + lane] = c2 * inv;
    if (jch == 0 && lane == 0 && k < P_N) {
      pp[k] = q * inv * inv;              // ||p_hat||^2
      sp[k] = s * inv;                    // sum(p_hat)
    }
  }
  __syncthreads();

  const int j = jch * 256 + tid;
  float acc[12];
#pragma unroll
  for (int kk = 0; kk < 12; ++kk) acc[kk] = 0.0f;
  float zs = 0.0f, zq = 0.0f;
  const bool do_stats = (khalf == 0);
  const float* __restrict__ zrow = z + (size_t)j * Z_D;
  for (int i4 = 0; i4 < Z_D; i4 += 4) {
    const float4 zv = *(const float4*)(zrow + i4);
    if (do_stats) {
      zs += zv.x + zv.y + zv.z + zv.w;
      zq += zv.x * zv.x + zv.y * zv.y + zv.z * zv.z + zv.w * zv.w;
    }
#pragma unroll
    for (int kk = 0; kk < 12; ++kk) {
      const float4 pv = *(const float4*)(pt + kk * Z_D + i4);  // LDS broadcast
      acc[kk] += zv.x * pv.x + zv.y * pv.y + zv.z * pv.z + zv.w * pv.w;
    }
  }
  {
    float* gtp = GT + (size_t)j * GT_S + k0;   // k0 % 4 == 0 -> 16B aligned
    *(float4*)(gtp + 0) = make_float4(acc[0], acc[1], acc[2], acc[3]);
    *(float4*)(gtp + 4) = make_float4(acc[4], acc[5], acc[6], acc[7]);
    *(float4*)(gtp + 8) = make_float4(acc[8], acc[9], acc[10], acc[11]);
  }
  if (do_stats) {
    zz[j] = zq;
    sz[j] = zs;
    w[j] = zq - TWO_EPS * zs;   // per-j part of pdist(prox, z)
  }

  // --- wait for init flag, then grid barrier #1 ---------------------------
  if (tid == 0) {
    long long g = 0;
    while (__hip_atomic_load(flag, __ATOMIC_ACQUIRE, __HIP_MEMORY_SCOPE_AGENT) != MAGIC) {
      __builtin_amdgcn_s_sleep(2);
      if (++g > (1LL << 27)) break;
    }
  }
  gbar(bar0);

  // --- P2: per-anchor work. pp/sp cached in LDS (pt is free now). ---------
  float* lpp = pt;
  float* lsp = pt + 128;
  if (tid < P_N) { lpp[tid] = pp[tid]; lsp[tid] = sp[tid]; }
  __syncthreads();

  float lsum = 0.0f;
  for (int wid = b * 4 + wv; wid < A_N; wid += NBLK * 4) {
    const int i = 3 * wid;                 // anchor sample index
    const float zzi = zz[i], szi = sz[i];
    const int cls = yrel[i];
    const int k2 = lane + 64;

    // step a: nearest proxy to anchor (argmin, first-index tie-break)
    const float* __restrict__ GTi = GT + (size_t)i * GT_S;
    float v1 = fmaxf(zzi + lpp[lane] - 2.0f * GTi[lane] +
                     TWO_EPS * (szi - lsp[lane]) + ZEPS2, 0.0f);
    int i1 = lane;
    if (k2 < P_N) {
      const float v2 = fmaxf(zzi + lpp[k2] - 2.0f * GTi[k2] +
                             TWO_EPS * (szi - lsp[k2]) + ZEPS2, 0.0f);
      if (v2 < v1) { v1 = v2; i1 = k2; }
    }
#pragma unroll
    for (int off = 1; off < 64; off <<= 1) {
      const float ov = __shfl_xor(v1, off, 64);
      const int oi = __shfl_xor(i1, off, 64);
      if (ov < v1 || (ov == v1 && oi < i1)) { v1 = ov; i1 = oi; }
    }
    const int p = i1;

    // step b: hardest positive among same-class suffix (class bucket)
    const float cp = lpp[p] + TWO_EPS * lsp[p] + ZEPS2;
    const int n = cnt[cls];
    const int* __restrict__ bk = bkt + cls * BCAP;
    float best = -INFINITY;
    int bestj = 0x7fffffff;
    for (int t = lane; t < n; t += 64) {
      const int jj = bk[t];
      if (jj >= i) {
        const float v = fmaxf(cp + w[jj] - 2.0f * GT[(size_t)jj * GT_S + p], 0.0f);
        if (v > best || (v == best && jj < bestj)) { best = v; bestj = jj; }
      }
    }
#pragma unroll
    for (int off = 1; off < 64; off <<= 1) {
      const float ov = __shfl_xor(best, off, 64);
      const int oj = __shfl_xor(bestj, off, 64);
      if (ov > best || (ov == best && oj < bestj)) { best = ov; bestj = oj; }
    }
    const float Dp = sqrtf(best);
    const int jp = bestj;

    // step c: logsumexp(-D_n) over proxies
    const float zzj = zz[jp], szj = sz[jp];
    const float* __restrict__ GTj = GT + (size_t)jp * GT_S;
    const float d1 = sqrtf(fmaxf(zzj + lpp[lane] - 2.0f * GTj[lane] +
                                 TWO_EPS * (szj - lsp[lane]) + ZEPS2, 0.0f));
    float d2 = INFINITY;
    if (k2 < P_N)
      d2 = sqrtf(fmaxf(zzj + lpp[k2] - 2.0f * GTj[k2] +
                       TWO_EPS * (szj - lsp[k2]) + ZEPS2, 0.0f));
    const float m = wave_min(fminf(d1, d2));
    float ssum = expf(m - d1) + ((k2 < P_N) ? expf(m - d2) : 0.0f);
    ssum = wave_sum(ssum);
    lsum += Dp - m + logf(ssum);           // uniform across the wave
  }
  if (lane == 0) part[wv] = lsum;
  __syncthreads();
  if (tid == 0) atomicAdd(accf, part[0] + part[1] + part[2] + part[3]);

  // --- grid barrier #2, then block 0 writes the mean ----------------------
  gbar(bar1);
  if (b == 0 && tid == 0)
    out[0] = __hip_atomic_load(accf, __ATOMIC_RELAXED, __HIP_MEMORY_SCOPE_AGENT)
             * (1.0f / (float)A_N);
}

extern "C" void kernel_launch(void* const* d_in, const int* in_sizes, int n_in,
                              void* d_out, int out_size, void* d_ws, size_t ws_size,
                              hipStream_t stream) {
  const float* z = (const float*)d_in[0];      // [8192,128] f32
  const int* y_idx = (const int*)d_in[1];      // [8192] i32
  const float* prox = (const float*)d_in[2];   // [93,128] f32
  const int* y_map = (const int*)d_in[3];      // [62] i32
  float* out = (float*)d_out;

  // workspace layout (bytes) — total ~3.35 MB
  char* ws = (char*)d_ws;
  int*   flag = (int*)  (ws + 0);              // separate cache lines
  int*   bar0 = (int*)  (ws + 64);
  int*   bar1 = (int*)  (ws + 128);
  float* accf = (float*)(ws + 192);
  float* pp   = (float*)(ws + 256);            // 96*4 -> 640
  float* sp   = (float*)(ws + 640);            // -> 1024
  float* zz   = (float*)(ws + 1024);           // 8192*4 -> 33792
  float* sz   = (float*)(ws + 33792);          // -> 66560
  float* w    = (float*)(ws + 66560);          // -> 99328
  int*   yrel = (int*)  (ws + 99328);          // -> 132096
  int*   cnt  = (int*)  (ws + 132096);         // 62*4 -> 132352 (padded)
  int*   bkt  = (int*)  (ws + 132352);         // 62*256*4 -> 195840
  float* GT   = (float*)(ws + 195840);         // 8192*96*4 -> 3341568 (16B-aligned)

  kFused<<<NBLK, 256, 0, stream>>>(z, y_idx, prox, y_map, out,
                                   flag, bar0, bar1, accf,
                                   pp, sp, zz, sz, w, yrel, cnt, bkt, GT);
}

// Round 5
// 106.317 us; speedup vs baseline: 1.6215x; 1.6215x over previous
//
#include <hip/hip_runtime.h>
#include <math.h>

// Problem constants (match reference setup_inputs)
#define B_N   8192      // samples
#define Z_D   128       // feature dim
#define P_N   93        // proxies
#define NCLS  62        // classes
#define A_N   2730      // anchors: arange(0, 8189, 3)
#define BCAP  256       // class-bucket capacity (max expected ~180)
#define NBLK  256       // blocks (== CU count, all co-resident)
#define BLKT  512       // threads/block (8 waves/CU)
#define MAGIC 0x5eedf00du
#define TWO_EPS   2e-6f
#define ZEPS2     (128.0f * 1e-6f * 1e-6f)

// Relaxed agent-scope atomics: sc-bit write-through/bypass, NO buffer_wbl2 /
// buffer_inv cache maintenance (R4's acquire/release storm cost ~100us).
#define AT_LD(p)     __hip_atomic_load((p), __ATOMIC_RELAXED, __HIP_MEMORY_SCOPE_AGENT)
#define AT_ST(p, v)  __hip_atomic_store((p), (v), __ATOMIC_RELAXED, __HIP_MEMORY_SCOPE_AGENT)
#define AT_ADD(p, v) __hip_atomic_fetch_add((p), (v), __ATOMIC_RELAXED, __HIP_MEMORY_SCOPE_AGENT)

__device__ __forceinline__ float wave_sum(float v) {
#pragma unroll
  for (int off = 1; off < 64; off <<= 1) v += __shfl_xor(v, off, 64);
  return v;
}
__device__ __forceinline__ float wave_min(float v) {
#pragma unroll
  for (int off = 1; off < 64; off <<= 1) v = fminf(v, __shfl_xor(v, off, 64));
  return v;
}

__global__ __launch_bounds__(BLKT) void kFused(
    const float* __restrict__ z, const int* __restrict__ y_idx,
    const float* __restrict__ prox, const int* __restrict__ y_map,
    float* __restrict__ out,
    unsigned int* flag, unsigned int* bar0, unsigned int* bar1, float* accf,
    float* pp, float* sp, float* zz, float* sz, float* w,
    int* cnt, int* bkt, float* G) {
  __shared__ float pt[3 * Z_D];            // P1 proxy tile
  __shared__ float lpp[P_N], lsp[P_N];     // P2 proxy scalars
  __shared__ int lymap[NCLS];
  __shared__ float part[8];
  __shared__ int lcnt;
  const int b = blockIdx.x, tid = threadIdx.x;
  const int lane = tid & 63, wv = tid >> 6;

  // --- init (block 0): zero counters, then publish MAGIC after vmcnt drain.
  // ws is poisoned 0xAA pre-launch; 0xAAAAAAAA != MAGIC so protocol is safe.
  if (b == 0 && tid == 0) {
    AT_ST(bar0, 0u); AT_ST(bar1, 0u);
    __hip_atomic_store(accf, 0.0f, __ATOMIC_RELAXED, __HIP_MEMORY_SCOPE_AGENT);
    __builtin_amdgcn_s_waitcnt(0);         // zeros visible before flag
    AT_ST(flag, MAGIC);
  }

  // --- P0: class buckets (blocks 0..61), LDS counter, write-through stores.
  // y_map entries are unique => block c claims exactly class-c samples.
  if (b < NCLS) {
    if (tid == 0) lcnt = 0;
    __syncthreads();
    const int ym = y_map[b];
    for (int j = tid; j < B_N; j += BLKT) {
      if (y_idx[j] == ym) {
        const int pos = atomicAdd(&lcnt, 1);     // LDS atomic
        if (pos < BCAP) AT_ST(&bkt[b * BCAP + pos], j);
      }
    }
    __syncthreads();
    if (tid == 0) AT_ST(&cnt[b], min(lcnt, BCAP));
  }

  // --- P1: G[k][j] = p_hat_k . z_j, COLUMN-MAJOR (G[k*8192+j]) so stores
  // coalesce across lanes. 32 k-tiles x 3 proxies, 8 j-chunks x 1024 rows,
  // 2 rows/thread. Tile 31 (k=93..95 pad) computes zz/sz/w instead.
  const int jch = b & 7, kt = b >> 3, k0 = kt * 3;
  const int j0 = jch * 1024 + tid, j1 = j0 + 512;
  const float* __restrict__ zr0 = z + (size_t)j0 * Z_D;
  const float* __restrict__ zr1 = z + (size_t)j1 * Z_D;
  if (kt < 31) {
    if (wv < 3) {                          // normalize 3 proxy rows into LDS
      const int k = k0 + wv;               // k0<=90 => k<=92, in range
      const float a = prox[k * Z_D + lane];
      const float c2 = prox[k * Z_D + 64 + lane];
      const float s = wave_sum(a + c2);
      const float q = wave_sum(a * a + c2 * c2);
      const float inv = 1.0f / fmaxf(sqrtf(q), 1e-12f);
      pt[wv * Z_D + lane] = a * inv;
      pt[wv * Z_D + 64 + lane] = c2 * inv;
      if (jch == 0 && lane == 0) {
        AT_ST(&pp[k], q * inv * inv);      // ||p_hat||^2
        AT_ST(&sp[k], s * inv);            // sum(p_hat)
      }
    }
    __syncthreads();
    float a0 = 0, a1 = 0, a2 = 0, c0 = 0, c1 = 0, c2 = 0;
#pragma unroll 8
    for (int i4 = 0; i4 < Z_D; i4 += 4) {
      const float4 z0 = *(const float4*)(zr0 + i4);
      const float4 z1 = *(const float4*)(zr1 + i4);
      const float4 p0 = *(const float4*)(pt + 0 * Z_D + i4);
      const float4 p1 = *(const float4*)(pt + 1 * Z_D + i4);
      const float4 p2 = *(const float4*)(pt + 2 * Z_D + i4);
      a0 += z0.x * p0.x + z0.y * p0.y + z0.z * p0.z + z0.w * p0.w;
      a1 += z0.x * p1.x + z0.y * p1.y + z0.z * p1.z + z0.w * p1.w;
      a2 += z0.x * p2.x + z0.y * p2.y + z0.z * p2.z + z0.w * p2.w;
      c0 += z1.x * p0.x + z1.y * p0.y + z1.z * p0.z + z1.w * p0.w;
      c1 += z1.x * p1.x + z1.y * p1.y + z1.z * p1.z + z1.w * p1.w;
      c2 += z1.x * p2.x + z1.y * p2.y + z1.z * p2.z + z1.w * p2.w;
    }
    AT_ST(&G[(size_t)(k0 + 0) * B_N + j0], a0);   // lane-coalesced columns
    AT_ST(&G[(size_t)(k0 + 1) * B_N + j0], a1);
    AT_ST(&G[(size_t)(k0 + 2) * B_N + j0], a2);
    AT_ST(&G[(size_t)(k0 + 0) * B_N + j1], c0);
    AT_ST(&G[(size_t)(k0 + 1) * B_N + j1], c1);
    AT_ST(&G[(size_t)(k0 + 2) * B_N + j1], c2);
  } else {                                 // stats tile: zz/sz/w
    float s0 = 0, q0 = 0, s1 = 0, q1 = 0;
#pragma unroll 8
    for (int i4 = 0; i4 < Z_D; i4 += 4) {
      const float4 z0 = *(const float4*)(zr0 + i4);
      const float4 z1 = *(const float4*)(zr1 + i4);
      s0 += z0.x + z0.y + z0.z + z0.w;
      q0 += z0.x * z0.x + z0.y * z0.y + z0.z * z0.z + z0.w * z0.w;
      s1 += z1.x + z1.y + z1.z + z1.w;
      q1 += z1.x * z1.x + z1.y * z1.y + z1.z * z1.z + z1.w * z1.w;
    }
    AT_ST(&zz[j0], q0); AT_ST(&sz[j0], s0); AT_ST(&w[j0], q0 - TWO_EPS * s0);
    AT_ST(&zz[j1], q1); AT_ST(&sz[j1], s1); AT_ST(&w[j1], q1 - TWO_EPS * s1);
  }

  // --- grid barrier: __syncthreads drains each wave's stores (compiler
  // emits vmcnt(0) before s_barrier); probes are pure RMWs (coherent-point,
  // zero cache maintenance).
  __syncthreads();
  if (tid == 0) {
    int g = 0;
    while (AT_ADD(flag, 0u) != MAGIC) {            // wait init published
      __builtin_amdgcn_s_sleep(2);
      if (++g > (1 << 20)) break;
    }
    AT_ADD(bar0, 1u);                              // arrive
    g = 0;
    while (AT_ADD(bar0, 0u) < (unsigned)NBLK) {    // spin via RMW probe
      __builtin_amdgcn_s_sleep(16);
      if (++g > (1 << 20)) break;
    }
  }
  __syncthreads();

  // --- P2 staging: proxy scalars + class map into LDS -----------------------
  if (tid < P_N) { lpp[tid] = AT_LD(&pp[tid]); lsp[tid] = AT_LD(&sp[tid]); }
  if (tid < NCLS) lymap[tid] = y_map[tid];
  __syncthreads();

  // --- P2: one wave per anchor ----------------------------------------------
  float lsum = 0.0f;
  for (int wid = b * 8 + wv; wid < A_N; wid += NBLK * 8) {
    const int i = 3 * wid;
    const int yi = y_idx[i];
    const unsigned long long mm = __ballot(lane < NCLS && lymap[lane] == yi);
    const int cls = __ffsll(mm) - 1;       // unique match (y_map unique)
    const float zzi = AT_LD(&zz[i]), szi = AT_LD(&sz[i]);
    const int kB = lane + 64;

    // step a: nearest proxy (argmin, first-index tie-break)
    float v1 = fmaxf(zzi + lpp[lane] - 2.0f * AT_LD(&G[(size_t)lane * B_N + i]) +
                     TWO_EPS * (szi - lsp[lane]) + ZEPS2, 0.0f);
    int i1 = lane;
    if (kB < P_N) {
      const float v2 = fmaxf(zzi + lpp[kB] - 2.0f * AT_LD(&G[(size_t)kB * B_N + i]) +
                             TWO_EPS * (szi - lsp[kB]) + ZEPS2, 0.0f);
      if (v2 < v1) { v1 = v2; i1 = kB; }
    }
#pragma unroll
    for (int off = 1; off < 64; off <<= 1) {
      const float ov = __shfl_xor(v1, off, 64);
      const int oi = __shfl_xor(i1, off, 64);
      if (ov < v1 || (ov == v1 && oi < i1)) { v1 = ov; i1 = oi; }
    }
    const int p = i1;

    // step b: hardest positive in same-class suffix (bucket scan)
    const float cp = lpp[p] + TWO_EPS * lsp[p] + ZEPS2;
    const int n = AT_LD(&cnt[cls]);
    int* bk = bkt + cls * BCAP;
    float best = -INFINITY;
    int bestj = 0x7fffffff;
    for (int t = lane; t < n; t += 64) {
      const int jj = AT_LD(&bk[t]);
      if (jj >= i) {
        const float vv = fmaxf(cp + AT_LD(&w[jj]) -
                               2.0f * AT_LD(&G[(size_t)p * B_N + jj]), 0.0f);
        if (vv > best || (vv == best && jj < bestj)) { best = vv; bestj = jj; }
      }
    }
#pragma unroll
    for (int off = 1; off < 64; off <<= 1) {
      const float ov = __shfl_xor(best, off, 64);
      const int oj = __shfl_xor(bestj, off, 64);
      if (ov > best || (ov == best && oj < bestj)) { best = ov; bestj = oj; }
    }
    const float Dp = sqrtf(best);
    const int jp = bestj;

    // step c: logsumexp(-D_n) over proxies
    const float zzj = AT_LD(&zz[jp]), szj = AT_LD(&sz[jp]);
    const float d1 = sqrtf(fmaxf(zzj + lpp[lane] -
                                 2.0f * AT_LD(&G[(size_t)lane * B_N + jp]) +
                                 TWO_EPS * (szj - lsp[lane]) + ZEPS2, 0.0f));
    float d2 = INFINITY;
    if (kB < P_N)
      d2 = sqrtf(fmaxf(zzj + lpp[kB] -
                       2.0f * AT_LD(&G[(size_t)kB * B_N + jp]) +
                       TWO_EPS * (szj - lsp[kB]) + ZEPS2, 0.0f));
    const float mn = wave_min(fminf(d1, d2));
    float ss = expf(mn - d1) + ((kB < P_N) ? expf(mn - d2) : 0.0f);
    ss = wave_sum(ss);
    lsum += Dp - mn + logf(ss);
  }
  if (lane == 0) part[wv] = lsum;
  __syncthreads();

  // --- finalize: block partial -> coherent add; LAST arriver writes mean.
  if (tid == 0) {
    const float tot = part[0] + part[1] + part[2] + part[3] +
                      part[4] + part[5] + part[6] + part[7];
    AT_ADD(accf, tot);
    __builtin_amdgcn_s_waitcnt(0);         // our add at coherence point
    const unsigned old = AT_ADD(bar1, 1u);
    if (old == (unsigned)(NBLK - 1))       // everyone's add is done
      out[0] = AT_ADD(accf, 0.0f) * (1.0f / (float)A_N);
  }
}

extern "C" void kernel_launch(void* const* d_in, const int* in_sizes, int n_in,
                              void* d_out, int out_size, void* d_ws, size_t ws_size,
                              hipStream_t stream) {
  const float* z = (const float*)d_in[0];      // [8192,128] f32
  const int* y_idx = (const int*)d_in[1];      // [8192] i32
  const float* prox = (const float*)d_in[2];   // [93,128] f32
  const int* y_map = (const int*)d_in[3];      // [62] i32
  float* out = (float*)d_out;

  // workspace layout (bytes), ~3.21 MB
  char* ws = (char*)d_ws;
  unsigned int* flag = (unsigned int*)(ws + 0);
  unsigned int* bar0 = (unsigned int*)(ws + 64);
  unsigned int* bar1 = (unsigned int*)(ws + 128);
  float* accf = (float*)(ws + 192);
  float* pp   = (float*)(ws + 256);            // 93*4 (pad to 512)
  float* sp   = (float*)(ws + 768);            // 93*4 (pad to 512)
  float* zz   = (float*)(ws + 1280);           // 8192*4 -> 34048
  float* sz   = (float*)(ws + 34048);          // -> 66816
  float* w    = (float*)(ws + 66816);          // -> 99584
  int*   cnt  = (int*)  (ws + 99584);          // 62*4 (pad 256) -> 99840
  int*   bkt  = (int*)  (ws + 99840);          // 62*256*4 -> 163328
  float* G    = (float*)(ws + 163328);         // 93*8192*4 col-major -> 3210752

  kFused<<<NBLK, BLKT, 0, stream>>>(z, y_idx, prox, y_map, out,
                                    flag, bar0, bar1, accf,
                                    pp, sp, zz, sz, w, cnt, bkt, G);
}